// Round 1
// baseline (456.136 us; speedup 1.0000x reference)
//
#include <hip/hip_runtime.h>
#include <stdint.h>

typedef unsigned short u16;
typedef __attribute__((ext_vector_type(8))) short short8;
typedef __attribute__((ext_vector_type(4))) float f32x4;

#define B_ 2
#define S_ 2048
#define E_ 2048
#define H_ 16
#define D_ 128
#define M_ 4096

__device__ __forceinline__ u16 f2bf(float f) {
  unsigned u = __float_as_uint(f);
  u = u + 0x7FFFu + ((u >> 16) & 1u);
  return (u16)(u >> 16);
}
__device__ __forceinline__ float bf2f(u16 h) {
  return __uint_as_float(((unsigned)h) << 16);
}

// async global->LDS, 16B per lane; LDS dest is wave-uniform base + lane*16
#define GLD16(gp, lp) __builtin_amdgcn_global_load_lds(                      \
    (__attribute__((address_space(1))) void*)(gp),                           \
    (__attribute__((address_space(3))) void*)(lp), 16, 0, 0)

// ---------------------------------------------------------------- cast f32->bf16
__global__ void cast_bf16(const float4* __restrict__ src, ushort4* __restrict__ dst, int n4) {
  int i = blockIdx.x * 256 + threadIdx.x;
  if (i < n4) {
    float4 v = src[i];
    ushort4 o;
    o.x = f2bf(v.x); o.y = f2bf(v.y); o.z = f2bf(v.z); o.w = f2bf(v.w);
    dst[i] = o;
  }
}

// ---------------------------------------------------------------- GEMM  C = A[M,K] @ W[N,K]^T
// m97-style: 128x128 tile, BK=32, 4 waves (each 64x64 = 4x4 frags of 16x16x32)
// MODE 0: write bf16 scattered to [B,H,S,D]   MODE 1: write f32 row-major [M,N]
template <int MODE>
__launch_bounds__(256, 2)
__global__ void gemm_bt(const u16* __restrict__ A, const u16* __restrict__ Bw,
                        void* __restrict__ Cp, int M, int N, int K) {
  __shared__ alignas(16) u16 As[128 * 32];
  __shared__ alignas(16) u16 Bs[128 * 32];
  const int tid = threadIdx.x;
  const int wave = tid >> 6, lane = tid & 63;
  const int m0 = blockIdx.y * 128, n0 = blockIdx.x * 128;
  const int wr = (wave >> 1) * 64, wc = (wave & 1) * 64;
  const int lrow = lane & 15, lk = (lane >> 4) * 8;
  f32x4 acc[4][4] = {};

  for (int k0 = 0; k0 < K; k0 += 32) {
#pragma unroll
    for (int q = 0; q < 2; ++q) {
      const int g = q * 4 + wave;        // 0..7 (wave-uniform)
      const int c = g * 64 + lane;       // 16B-chunk id, 0..511
      const int row = c >> 2, ch = (c & 3) * 8;
      GLD16(A + (size_t)(m0 + row) * K + k0 + ch, &As[g * 512]);
      GLD16(Bw + (size_t)(n0 + row) * K + k0 + ch, &Bs[g * 512]);
    }
    __syncthreads();
    short8 a[4], b[4];
#pragma unroll
    for (int m = 0; m < 4; ++m) a[m] = *(const short8*)&As[(wr + m * 16 + lrow) * 32 + lk];
#pragma unroll
    for (int n = 0; n < 4; ++n) b[n] = *(const short8*)&Bs[(wc + n * 16 + lrow) * 32 + lk];
#pragma unroll
    for (int m = 0; m < 4; ++m)
#pragma unroll
      for (int n = 0; n < 4; ++n)
        acc[m][n] = __builtin_amdgcn_mfma_f32_16x16x32_bf16(a[m], b[n], acc[m][n], 0, 0, 0);
    __syncthreads();
  }

  const int rbase = (lane >> 4) * 4;  // C/D: col = lane&15, row = (lane>>4)*4 + r
#pragma unroll
  for (int m = 0; m < 4; ++m)
#pragma unroll
    for (int n = 0; n < 4; ++n)
#pragma unroll
      for (int r = 0; r < 4; ++r) {
        const int mm = m0 + wr + m * 16 + rbase + r;
        const int nn = n0 + wc + n * 16 + lrow;
        const float v = acc[m][n][r];
        if (MODE == 0) {
          const int bb = mm >> 11, s = mm & (S_ - 1), h = nn >> 7, d = nn & (D_ - 1);
          ((u16*)Cp)[(((size_t)bb * H_ + h) * S_ + s) * D_ + d] = f2bf(v);
        } else {
          ((float*)Cp)[(size_t)mm * N + nn] = v;
        }
      }
}

// ---------------------------------------------------------------- RoPE (NeoX) in-place on [B,H,S,D] bf16
__global__ void rope_k(u16* __restrict__ T, const float* __restrict__ cosT, const float* __restrict__ sinT) {
  const int idx = blockIdx.x * 256 + threadIdx.x;  // B*H*S*64 threads
  const int row = idx >> 6;                        // (b*H+h)*S + s
  const int d = idx & 63;
  const int s = row & (S_ - 1);
  const float c1 = cosT[s * D_ + d], s1 = sinT[s * D_ + d];
  const float c2 = cosT[s * D_ + d + 64], s2 = sinT[s * D_ + d + 64];
  const size_t base = (size_t)row * D_;
  const float x1 = bf2f(T[base + d]), x2 = bf2f(T[base + d + 64]);
  T[base + d]      = f2bf(x1 * c1 - x2 * s1);
  T[base + d + 64] = f2bf(x2 * c2 + x1 * s2);
}

// ---------------------------------------------------------------- V [B,H,S,D] -> VT [B,H,D,S]
__global__ void transpose64(const u16* __restrict__ V, u16* __restrict__ VT) {
  __shared__ alignas(16) u16 t[64][72];
  const int bh = blockIdx.z, st = blockIdx.y * 64, dt = blockIdx.x * 64;
  const u16* Vp = V + (size_t)bh * S_ * D_;
  u16* Tp = VT + (size_t)bh * D_ * S_;
  const int tid = threadIdx.x;
#pragma unroll
  for (int p = 0; p < 2; ++p) {
    const int idx = p * 256 + tid;
    const int r = idx >> 3, c8 = (idx & 7) * 8;
    *(short8*)&t[r][c8] = *(const short8*)&Vp[(size_t)(st + r) * D_ + dt + c8];
  }
  __syncthreads();
#pragma unroll
  for (int p = 0; p < 2; ++p) {
    const int idx = p * 256 + tid;
    const int dr = idx >> 3, s8 = (idx & 7) * 8;
    short8 v;
#pragma unroll
    for (int j = 0; j < 8; ++j) v[j] = t[s8 + j][dr];
    *(short8*)&Tp[(size_t)(dt + dr) * S_ + st + s8] = v;
  }
}

// ---------------------------------------------------------------- causal flash attention
// grid (S/64 qblocks, B*H). 4 waves x 16 q-rows. K tile [64][128], VT tile [128][64],
// both staged with XOR-preswizzled global source so ds_read_b128 frags are conflict-free.
__launch_bounds__(256, 2)
__global__ void attn_fwd(const u16* __restrict__ Q, const u16* __restrict__ Kt,
                         const u16* __restrict__ VT, u16* __restrict__ Out) {
  __shared__ alignas(16) u16 Kl[64 * 128];
  __shared__ alignas(16) u16 Vl[128 * 64];
  __shared__ alignas(16) u16 Pl[4][16 * 64];
  const int tid = threadIdx.x, wave = tid >> 6, lane = tid & 63;
  const int qb = blockIdx.x, bh = blockIdx.y;
  const int bb = bh >> 4, h = bh & 15;
  const u16* Qh = Q + (size_t)bh * S_ * D_;
  const u16* Kh = Kt + (size_t)bh * S_ * D_;
  const u16* Vh = VT + (size_t)bh * D_ * S_;
  const int lrow = lane & 15, lkb = (lane >> 4) * 8;
  const int q0 = qb * 64 + wave * 16;

  short8 qf[4];
#pragma unroll
  for (int dk = 0; dk < 4; ++dk)
    qf[dk] = *(const short8*)&Qh[(size_t)(q0 + lrow) * D_ + dk * 32 + lkb];

  f32x4 po[8] = {};
  float mr[4], lsum[4];
#pragma unroll
  for (int r = 0; r < 4; ++r) { mr[r] = -1e30f; lsum[r] = 0.f; }

  // scores tracked in log2 units: s2 = raw * (1/sqrt(D)) * log2(e)
  const float sscale = 0.08838834764831845f * 1.4426950408889634f;
  const int ntiles = qb + 1;

  for (int t = 0; t < ntiles; ++t) {
    const int kv0 = t * 64;
#pragma unroll
    for (int p = 0; p < 4; ++p) {
      const int g = p * 4 + wave;     // 0..15 (wave-uniform)
      const int c = g * 64 + lane;    // 0..1023
      const int srow = c >> 4, dch = c & 15;
      GLD16(Kh + (size_t)(kv0 + srow) * D_ + ((dch ^ (srow & 7)) * 8), &Kl[g * 512]);
      const int drow = c >> 3, sch = c & 7;
      GLD16(Vh + (size_t)drow * S_ + kv0 + ((sch ^ (drow & 7)) * 8), &Vl[g * 512]);
    }
    __syncthreads();

    // QK^T : 16 MFMA per wave
    f32x4 sc[4] = {};
#pragma unroll
    for (int n = 0; n < 4; ++n) {
      const int row = n * 16 + lrow;
#pragma unroll
      for (int dk = 0; dk < 4; ++dk) {
        const int kk = dk * 32 + lkb;
        short8 kf = *(const short8*)&Kl[row * 128 + (kk ^ ((row & 7) << 3))];
        sc[n] = __builtin_amdgcn_mfma_f32_16x16x32_bf16(qf[dk], kf, sc[n], 0, 0, 0);
      }
    }

    const bool diag = (t == qb);
    float pval[4][4];
#pragma unroll
    for (int n = 0; n < 4; ++n)
#pragma unroll
      for (int r = 0; r < 4; ++r) {
        float s = sc[n][r] * sscale;
        if (diag) {
          const int qg = q0 + (lane >> 4) * 4 + r;
          const int kg = kv0 + n * 16 + lrow;
          if (kg > qg) s = -1e30f;
        }
        pval[n][r] = s;
      }

    // online softmax, wave-parallel row reduce (cols live on lane bits 0..3)
#pragma unroll
    for (int r = 0; r < 4; ++r) {
      float mx = fmaxf(fmaxf(pval[0][r], pval[1][r]), fmaxf(pval[2][r], pval[3][r]));
      mx = fmaxf(mx, __shfl_xor(mx, 1));
      mx = fmaxf(mx, __shfl_xor(mx, 2));
      mx = fmaxf(mx, __shfl_xor(mx, 4));
      mx = fmaxf(mx, __shfl_xor(mx, 8));
      const float mnew = fmaxf(mr[r], mx);
      const float corr = exp2f(mr[r] - mnew);
      float ps = 0.f;
#pragma unroll
      for (int n = 0; n < 4; ++n) {
        const float p = exp2f(pval[n][r] - mnew);
        pval[n][r] = p;
        ps += p;
      }
      ps += __shfl_xor(ps, 1);
      ps += __shfl_xor(ps, 2);
      ps += __shfl_xor(ps, 4);
      ps += __shfl_xor(ps, 8);
      lsum[r] = lsum[r] * corr + ps;
      mr[r] = mnew;
#pragma unroll
      for (int dn = 0; dn < 8; ++dn) po[dn][r] *= corr;
    }

    // P -> per-wave LDS (swizzled), then PV
    u16* Pw = &Pl[wave][0];
#pragma unroll
    for (int n = 0; n < 4; ++n)
#pragma unroll
      for (int r = 0; r < 4; ++r) {
        const int row = (lane >> 4) * 4 + r;
        const int col = n * 16 + lrow;
        Pw[row * 64 + (col ^ ((row & 7) << 3))] = f2bf(pval[n][r]);
      }
#pragma unroll
    for (int kk2 = 0; kk2 < 2; ++kk2) {
      const int kbase = kk2 * 32 + lkb;
      short8 pf = *(const short8*)&Pw[lrow * 64 + (kbase ^ ((lrow & 7) << 3))];
#pragma unroll
      for (int dn = 0; dn < 8; ++dn) {
        const int drow = dn * 16 + lrow;
        short8 vf = *(const short8*)&Vl[drow * 64 + (kbase ^ ((drow & 7) << 3))];
        po[dn] = __builtin_amdgcn_mfma_f32_16x16x32_bf16(pf, vf, po[dn], 0, 0, 0);
      }
    }
    __syncthreads();
  }

  // finalize: o /= l, write bf16 to attn buffer laid out [B,S,E]
#pragma unroll
  for (int r = 0; r < 4; ++r) {
    const float inv = 1.f / lsum[r];
    const int qg = q0 + (lane >> 4) * 4 + r;
    const size_t base = ((size_t)bb * S_ + qg) * E_ + h * D_;
#pragma unroll
    for (int dn = 0; dn < 8; ++dn)
      Out[base + dn * 16 + lrow] = f2bf(po[dn][r] * inv);
  }
}

// ---------------------------------------------------------------- launcher
extern "C" void kernel_launch(void* const* d_in, const int* in_sizes, int n_in,
                              void* d_out, int out_size, void* d_ws, size_t ws_size,
                              hipStream_t stream) {
  const float* x    = (const float*)d_in[0];
  const float* cosT = (const float*)d_in[1];
  const float* sinT = (const float*)d_in[2];
  const float* Wq   = (const float*)d_in[3];
  const float* Wk   = (const float*)d_in[4];
  const float* Wv   = (const float*)d_in[5];
  const float* Wo   = (const float*)d_in[6];
  float* out = (float*)d_out;

  const size_t NX = (size_t)B_ * S_ * E_;  // 8388608
  const size_t NW = (size_t)E_ * E_;       // 4194304
  u16* ws  = (u16*)d_ws;
  u16* xb  = ws;
  u16* Wqb = xb + NX;
  u16* Wkb = Wqb + NW;
  u16* Wvb = Wkb + NW;
  u16* Wob = Wvb + NW;
  u16* Qb  = Wob + NW;
  u16* Kb  = Qb + NX;
  u16* Vb  = Kb + NX;
  u16* VTb = Vb + NX;
  u16* Ab  = VTb + NX;

  cast_bf16<<<(int)(NX / 4 / 256), 256, 0, stream>>>((const float4*)x, (ushort4*)xb, (int)(NX / 4));
  cast_bf16<<<(int)(NW / 4 / 256), 256, 0, stream>>>((const float4*)Wq, (ushort4*)Wqb, (int)(NW / 4));
  cast_bf16<<<(int)(NW / 4 / 256), 256, 0, stream>>>((const float4*)Wk, (ushort4*)Wkb, (int)(NW / 4));
  cast_bf16<<<(int)(NW / 4 / 256), 256, 0, stream>>>((const float4*)Wv, (ushort4*)Wvb, (int)(NW / 4));
  cast_bf16<<<(int)(NW / 4 / 256), 256, 0, stream>>>((const float4*)Wo, (ushort4*)Wob, (int)(NW / 4));

  dim3 gg(E_ / 128, M_ / 128);
  gemm_bt<0><<<gg, 256, 0, stream>>>(xb, Wqb, Qb, M_, E_, E_);
  gemm_bt<0><<<gg, 256, 0, stream>>>(xb, Wkb, Kb, M_, E_, E_);
  gemm_bt<0><<<gg, 256, 0, stream>>>(xb, Wvb, Vb, M_, E_, E_);

  rope_k<<<(B_ * H_ * S_ * 64) / 256, 256, 0, stream>>>(Qb, cosT, sinT);
  rope_k<<<(B_ * H_ * S_ * 64) / 256, 256, 0, stream>>>(Kb, cosT, sinT);

  transpose64<<<dim3(D_ / 64, S_ / 64, B_ * H_), 256, 0, stream>>>(Vb, VTb);

  attn_fwd<<<dim3(S_ / 64, B_ * H_), 256, 0, stream>>>(Qb, Kb, VTb, Ab);

  gemm_bt<1><<<gg, 256, 0, stream>>>(Ab, Wob, out, M_, E_, E_);
}

// Round 2
// 339.875 us; speedup vs baseline: 1.3421x; 1.3421x over previous
//
#include <hip/hip_runtime.h>
#include <stdint.h>

typedef unsigned short u16;
typedef __attribute__((ext_vector_type(8))) short short8;
typedef __attribute__((ext_vector_type(4))) float f32x4;

#define B_ 2
#define S_ 2048
#define E_ 2048
#define H_ 16
#define D_ 128
#define M_ 4096

__device__ __forceinline__ u16 f2bf(float f) {
  unsigned u = __float_as_uint(f);
  u = u + 0x7FFFu + ((u >> 16) & 1u);
  return (u16)(u >> 16);
}
__device__ __forceinline__ float bf2f(u16 h) {
  return __uint_as_float(((unsigned)h) << 16);
}

// async global->LDS, 16B per lane; LDS dest is wave-uniform base + lane*16
#define GLD16(gp, lp) __builtin_amdgcn_global_load_lds(                      \
    (__attribute__((address_space(1))) void*)(gp),                           \
    (__attribute__((address_space(3))) void*)(lp), 16, 0, 0)

// ---------------------------------------------------------------- cast f32->bf16
__global__ void cast_bf16(const float4* __restrict__ src, ushort4* __restrict__ dst, int n4) {
  int i = blockIdx.x * 256 + threadIdx.x;
  if (i < n4) {
    float4 v = src[i];
    ushort4 o;
    o.x = f2bf(v.x); o.y = f2bf(v.y); o.z = f2bf(v.z); o.w = f2bf(v.w);
    dst[i] = o;
  }
}

// 4 weight casts in one launch (blockIdx.y selects the tensor)
__global__ void cast4_bf16(const float4* __restrict__ w0, const float4* __restrict__ w1,
                           const float4* __restrict__ w2, const float4* __restrict__ w3,
                           ushort4* __restrict__ o0, ushort4* __restrict__ o1,
                           ushort4* __restrict__ o2, ushort4* __restrict__ o3, int n4) {
  const int i = blockIdx.x * 256 + threadIdx.x;
  if (i >= n4) return;
  const float4* s; ushort4* d;
  switch (blockIdx.y) {
    case 0: s = w0; d = o0; break;
    case 1: s = w1; d = o1; break;
    case 2: s = w2; d = o2; break;
    default: s = w3; d = o3; break;
  }
  float4 v = s[i];
  ushort4 o;
  o.x = f2bf(v.x); o.y = f2bf(v.y); o.z = f2bf(v.z); o.w = f2bf(v.w);
  d[i] = o;
}

// ---------------------------------------------------------------- GEMM  C = A[M,K] @ W[N,K]^T
// m97-style: 128x128 tile, BK=32, 4 waves (each 64x64 = 4x4 frags of 16x16x32)
// MODE 0: write bf16 scattered to [B,H,S,D]   MODE 1: write f32 row-major [M,N]
template <int MODE>
__launch_bounds__(256, 2)
__global__ void gemm_bt(const u16* __restrict__ A, const u16* __restrict__ Bw,
                        void* __restrict__ Cp, int M, int N, int K) {
  __shared__ alignas(16) u16 As[128 * 32];
  __shared__ alignas(16) u16 Bs[128 * 32];
  const int tid = threadIdx.x;
  const int wave = tid >> 6, lane = tid & 63;
  const int m0 = blockIdx.y * 128, n0 = blockIdx.x * 128;
  const int wr = (wave >> 1) * 64, wc = (wave & 1) * 64;
  const int lrow = lane & 15, lk = (lane >> 4) * 8;
  f32x4 acc[4][4] = {};

  for (int k0 = 0; k0 < K; k0 += 32) {
#pragma unroll
    for (int q = 0; q < 2; ++q) {
      const int g = q * 4 + wave;        // 0..7 (wave-uniform)
      const int c = g * 64 + lane;       // 16B-chunk id, 0..511
      const int row = c >> 2, ch = (c & 3) * 8;
      GLD16(A + (size_t)(m0 + row) * K + k0 + ch, &As[g * 512]);
      GLD16(Bw + (size_t)(n0 + row) * K + k0 + ch, &Bs[g * 512]);
    }
    __syncthreads();
    short8 a[4], b[4];
#pragma unroll
    for (int m = 0; m < 4; ++m) a[m] = *(const short8*)&As[(wr + m * 16 + lrow) * 32 + lk];
#pragma unroll
    for (int n = 0; n < 4; ++n) b[n] = *(const short8*)&Bs[(wc + n * 16 + lrow) * 32 + lk];
#pragma unroll
    for (int m = 0; m < 4; ++m)
#pragma unroll
      for (int n = 0; n < 4; ++n)
        acc[m][n] = __builtin_amdgcn_mfma_f32_16x16x32_bf16(a[m], b[n], acc[m][n], 0, 0, 0);
    __syncthreads();
  }

  const int rbase = (lane >> 4) * 4;  // C/D: col = lane&15, row = (lane>>4)*4 + r
#pragma unroll
  for (int m = 0; m < 4; ++m)
#pragma unroll
    for (int n = 0; n < 4; ++n)
#pragma unroll
      for (int r = 0; r < 4; ++r) {
        const int mm = m0 + wr + m * 16 + rbase + r;
        const int nn = n0 + wc + n * 16 + lrow;
        const float v = acc[m][n][r];
        if (MODE == 0) {
          const int bb = mm >> 11, s = mm & (S_ - 1), h = nn >> 7, d = nn & (D_ - 1);
          ((u16*)Cp)[(((size_t)bb * H_ + h) * S_ + s) * D_ + d] = f2bf(v);
        } else {
          ((float*)Cp)[(size_t)mm * N + nn] = v;
        }
      }
}

// ---------------------------------------------------------------- RoPE (NeoX) in-place on Q and K, [B,H,S,D] bf16
__global__ void rope2_k(u16* __restrict__ Qb, u16* __restrict__ Kb,
                        const float* __restrict__ cosT, const float* __restrict__ sinT) {
  u16* T = blockIdx.y ? Kb : Qb;
  const int idx = blockIdx.x * 256 + threadIdx.x;  // B*H*S*64 threads per tensor
  const int row = idx >> 6;                        // (b*H+h)*S + s
  const int d = idx & 63;
  const int s = row & (S_ - 1);
  const float c1 = cosT[s * D_ + d], s1 = sinT[s * D_ + d];
  const float c2 = cosT[s * D_ + d + 64], s2 = sinT[s * D_ + d + 64];
  const size_t base = (size_t)row * D_;
  const float x1 = bf2f(T[base + d]), x2 = bf2f(T[base + d + 64]);
  T[base + d]      = f2bf(x1 * c1 - x2 * s1);
  T[base + d + 64] = f2bf(x2 * c2 + x1 * s2);
}

// ---------------------------------------------------------------- V [B,H,S,D] -> VT [B,H,D,S]
__global__ void transpose64(const u16* __restrict__ V, u16* __restrict__ VT) {
  __shared__ alignas(16) u16 t[64][72];
  const int bh = blockIdx.z, st = blockIdx.y * 64, dt = blockIdx.x * 64;
  const u16* Vp = V + (size_t)bh * S_ * D_;
  u16* Tp = VT + (size_t)bh * D_ * S_;
  const int tid = threadIdx.x;
#pragma unroll
  for (int p = 0; p < 2; ++p) {
    const int idx = p * 256 + tid;
    const int r = idx >> 3, c8 = (idx & 7) * 8;
    *(short8*)&t[r][c8] = *(const short8*)&Vp[(size_t)(st + r) * D_ + dt + c8];
  }
  __syncthreads();
#pragma unroll
  for (int p = 0; p < 2; ++p) {
    const int idx = p * 256 + tid;
    const int dr = idx >> 3, s8 = (idx & 7) * 8;
    short8 v;
#pragma unroll
    for (int j = 0; j < 8; ++j) v[j] = t[s8 + j][dr];
    *(short8*)&Tp[(size_t)(dt + dr) * S_ + st + s8] = v;
  }
}

// ---------------------------------------------------------------- causal flash attention v2
// 512 blocks x 4 waves. Block = q-tile pair (31-p, p) -> uniform 33 KV-tiles per block.
// K/V double-buffered in LDS, ONE barrier per KV tile (stage(next) -> compute(cur) -> barrier).
// XOR-preswizzled global source so ds_read_b128 frags are ~conflict-free. setprio around MFMA.
__launch_bounds__(256, 2)
__global__ void attn_fwd(const u16* __restrict__ Q, const u16* __restrict__ Kt,
                         const u16* __restrict__ VT, u16* __restrict__ Out) {
  __shared__ alignas(16) u16 Kl[2][64 * 128];
  __shared__ alignas(16) u16 Vl[2][128 * 64];
  __shared__ alignas(16) u16 Pl[4][16 * 64];
  const int tid = threadIdx.x, wave = tid >> 6, lane = tid & 63;
  // bijective XCD swizzle (512 % 8 == 0): cluster the 16 pair-blocks of each bh per XCD
  const int hwid = blockIdx.x;
  const int lid = (hwid & 7) * 64 + (hwid >> 3);
  const int p = lid & 15, bh = lid >> 4;
  const int bb = bh >> 4, h = bh & 15;
  const u16* Qh = Q + (size_t)bh * S_ * D_;
  const u16* Kh = Kt + (size_t)bh * S_ * D_;
  const u16* Vh = VT + (size_t)bh * D_ * S_;
  const int lrow = lane & 15, lkb = (lane >> 4) * 8;

  auto stage = [&](int buf, int kv0) {
#pragma unroll
    for (int pp = 0; pp < 4; ++pp) {
      const int g = pp * 4 + wave;     // 0..15 (wave-uniform)
      const int c = g * 64 + lane;     // 0..1023
      const int srow = c >> 4, dch = c & 15;
      GLD16(Kh + (size_t)(kv0 + srow) * D_ + ((dch ^ (srow & 7)) * 8), &Kl[buf][g * 512]);
      const int drow = c >> 3, sch = c & 7;
      GLD16(Vh + (size_t)drow * S_ + kv0 + ((sch ^ (drow & 7)) * 8), &Vl[buf][g * 512]);
    }
  };

  // scores tracked in log2 units: s2 = raw * (1/sqrt(D)) * log2(e)
  const float sscale = 0.08838834764831845f * 1.4426950408889634f;
  int cur = 0;
  stage(0, 0);

  const int qts[2] = {31 - p, p};
#pragma unroll
  for (int seg = 0; seg < 2; ++seg) {
    const int qt = qts[seg];
    const int nt = qt + 1;
    const int q0 = qt * 64 + wave * 16;

    short8 qf[4];
#pragma unroll
    for (int dk = 0; dk < 4; ++dk)
      qf[dk] = *(const short8*)&Qh[(size_t)(q0 + lrow) * D_ + dk * 32 + lkb];

    f32x4 po[8] = {};
    float mr[4], lsum[4];
#pragma unroll
    for (int r = 0; r < 4; ++r) { mr[r] = -1e30f; lsum[r] = 0.f; }

    for (int t = 0; t < nt; ++t) {
      __syncthreads();  // buf[cur] staged AND all waves done reading buf[cur^1]
      if (t + 1 < nt)       stage(cur ^ 1, (t + 1) * 64);
      else if (seg == 0)    stage(cur ^ 1, 0);  // prefetch first tile of 2nd segment

      const int kv0 = t * 64;
      // QK^T : 16 MFMA per wave
      f32x4 sc[4] = {};
      __builtin_amdgcn_s_setprio(1);
#pragma unroll
      for (int n = 0; n < 4; ++n) {
        const int row = n * 16 + lrow;
#pragma unroll
        for (int dk = 0; dk < 4; ++dk) {
          const int kk = dk * 32 + lkb;
          short8 kf = *(const short8*)&Kl[cur][row * 128 + (kk ^ ((row & 7) << 3))];
          sc[n] = __builtin_amdgcn_mfma_f32_16x16x32_bf16(qf[dk], kf, sc[n], 0, 0, 0);
        }
      }
      __builtin_amdgcn_s_setprio(0);

      const bool diag = (t == qt);
      float pval[4][4];
#pragma unroll
      for (int n = 0; n < 4; ++n)
#pragma unroll
        for (int r = 0; r < 4; ++r) {
          float s = sc[n][r] * sscale;
          if (diag) {
            const int qg = q0 + (lane >> 4) * 4 + r;
            const int kg = kv0 + n * 16 + lrow;
            if (kg > qg) s = -1e30f;
          }
          pval[n][r] = s;
        }

      // online softmax, wave-parallel row reduce (k-cols live on lane bits 0..3)
#pragma unroll
      for (int r = 0; r < 4; ++r) {
        float mx = fmaxf(fmaxf(pval[0][r], pval[1][r]), fmaxf(pval[2][r], pval[3][r]));
        mx = fmaxf(mx, __shfl_xor(mx, 1));
        mx = fmaxf(mx, __shfl_xor(mx, 2));
        mx = fmaxf(mx, __shfl_xor(mx, 4));
        mx = fmaxf(mx, __shfl_xor(mx, 8));
        const float mnew = fmaxf(mr[r], mx);
        const float corr = exp2f(mr[r] - mnew);
        float ps = 0.f;
#pragma unroll
        for (int n = 0; n < 4; ++n) {
          const float pv = exp2f(pval[n][r] - mnew);
          pval[n][r] = pv;
          ps += pv;
        }
        ps += __shfl_xor(ps, 1);
        ps += __shfl_xor(ps, 2);
        ps += __shfl_xor(ps, 4);
        ps += __shfl_xor(ps, 8);
        lsum[r] = lsum[r] * corr + ps;
        mr[r] = mnew;
#pragma unroll
        for (int dn = 0; dn < 8; ++dn) po[dn][r] *= corr;
      }

      // P -> per-wave LDS (swizzled), then PV
      u16* Pw = &Pl[wave][0];
#pragma unroll
      for (int n = 0; n < 4; ++n)
#pragma unroll
        for (int r = 0; r < 4; ++r) {
          const int row = (lane >> 4) * 4 + r;
          const int col = n * 16 + lrow;
          Pw[row * 64 + (col ^ ((row & 7) << 3))] = f2bf(pval[n][r]);
        }
      __builtin_amdgcn_s_setprio(1);
#pragma unroll
      for (int kk2 = 0; kk2 < 2; ++kk2) {
        const int kbase = kk2 * 32 + lkb;
        short8 pf = *(const short8*)&Pw[lrow * 64 + (kbase ^ ((lrow & 7) << 3))];
#pragma unroll
        for (int dn = 0; dn < 8; ++dn) {
          const int drow = dn * 16 + lrow;
          short8 vf = *(const short8*)&Vl[cur][drow * 64 + (kbase ^ ((drow & 7) << 3))];
          po[dn] = __builtin_amdgcn_mfma_f32_16x16x32_bf16(pf, vf, po[dn], 0, 0, 0);
        }
      }
      __builtin_amdgcn_s_setprio(0);
      cur ^= 1;
    }

    // finalize segment: o /= l, write bf16 to attn buffer laid out [B,S,E]
#pragma unroll
    for (int r = 0; r < 4; ++r) {
      const float inv = 1.f / lsum[r];
      const int qg = q0 + (lane >> 4) * 4 + r;
      const size_t base = ((size_t)bb * S_ + qg) * E_ + h * D_;
#pragma unroll
      for (int dn = 0; dn < 8; ++dn)
        Out[base + dn * 16 + lrow] = f2bf(po[dn][r] * inv);
    }
  }
}

// ---------------------------------------------------------------- launcher
extern "C" void kernel_launch(void* const* d_in, const int* in_sizes, int n_in,
                              void* d_out, int out_size, void* d_ws, size_t ws_size,
                              hipStream_t stream) {
  const float* x    = (const float*)d_in[0];
  const float* cosT = (const float*)d_in[1];
  const float* sinT = (const float*)d_in[2];
  const float* Wq   = (const float*)d_in[3];
  const float* Wk   = (const float*)d_in[4];
  const float* Wv   = (const float*)d_in[5];
  const float* Wo   = (const float*)d_in[6];
  float* out = (float*)d_out;

  const size_t NX = (size_t)B_ * S_ * E_;  // 8388608
  const size_t NW = (size_t)E_ * E_;       // 4194304
  u16* ws  = (u16*)d_ws;
  u16* xb  = ws;
  u16* Wqb = xb + NX;
  u16* Wkb = Wqb + NW;
  u16* Wvb = Wkb + NW;
  u16* Wob = Wvb + NW;
  u16* Qb  = Wob + NW;
  u16* Kb  = Qb + NX;
  u16* Vb  = Kb + NX;
  u16* VTb = Vb + NX;
  u16* Ab  = VTb + NX;

  cast_bf16<<<(int)(NX / 4 / 256), 256, 0, stream>>>((const float4*)x, (ushort4*)xb, (int)(NX / 4));
  cast4_bf16<<<dim3((int)(NW / 4 / 256), 4), 256, 0, stream>>>(
      (const float4*)Wq, (const float4*)Wk, (const float4*)Wv, (const float4*)Wo,
      (ushort4*)Wqb, (ushort4*)Wkb, (ushort4*)Wvb, (ushort4*)Wob, (int)(NW / 4));

  dim3 gg(E_ / 128, M_ / 128);
  gemm_bt<0><<<gg, 256, 0, stream>>>(xb, Wqb, Qb, M_, E_, E_);
  gemm_bt<0><<<gg, 256, 0, stream>>>(xb, Wkb, Kb, M_, E_, E_);
  gemm_bt<0><<<gg, 256, 0, stream>>>(xb, Wvb, Vb, M_, E_, E_);

  rope2_k<<<dim3((B_ * H_ * S_ * 64) / 256, 2), 256, 0, stream>>>(Qb, Kb, cosT, sinT);

  transpose64<<<dim3(D_ / 64, S_ / 64, B_ * H_), 256, 0, stream>>>(Vb, VTb);

  attn_fwd<<<dim3(16 * 32), 256, 0, stream>>>(Qb, Kb, VTb, Ab);

  gemm_bt<1><<<gg, 256, 0, stream>>>(Ab, Wob, out, M_, E_, E_);
}